// Round 16
// baseline (351.467 us; speedup 1.0000x reference)
//
#include <hip/hip_runtime.h>
#include <math.h>

#define DD 64
#define HH 8
#define KORD 4

typedef __attribute__((ext_vector_type(8))) short bf16x8;
typedef __attribute__((ext_vector_type(4))) float f32x4;
typedef __attribute__((ext_vector_type(8))) unsigned short u16x8;
typedef __attribute__((ext_vector_type(4))) unsigned short u16x4;

__device__ __forceinline__ short f2bf(float f) {
    unsigned u = __builtin_bit_cast(unsigned, f);
    u = (u + 0x7fffu + ((u >> 16) & 1u)) >> 16;
    return (short)u;
}
__device__ __forceinline__ float bf2f(unsigned short u) {
    unsigned x = ((unsigned)u) << 16;
    return __builtin_bit_cast(float, x);
}
__device__ __forceinline__ float i2f(int v) { return __builtin_bit_cast(float, v); }

// ---------- fused: edge-count || weight-prep || hp bf16 cast ----------
__global__ void fused_init(const int* __restrict__ dst, int E, int* __restrict__ deg,
                           const float* __restrict__ WQ, const float* __restrict__ WK,
                           const float* __restrict__ WV, const float* __restrict__ Wc,
                           const float* __restrict__ Wg, const float* __restrict__ WE,
                           unsigned short* __restrict__ WQTp, unsigned short* __restrict__ WKTp,
                           unsigned short* __restrict__ WVT, unsigned short* __restrict__ WcT,
                           unsigned short* __restrict__ WgT, short* __restrict__ WETb,
                           const float* __restrict__ h, const float* __restrict__ p,
                           int n, unsigned short* __restrict__ hpb, int CB, int PRB) {
    int b = blockIdx.x, t = threadIdx.x;
    if (b < CB) {
        int i = b * 256 + t;
        if (i < E) atomicAdd(&deg[dst[i]], 1);
    } else if (b < CB + PRB) {
        int i = (b - CB) * 256 + t;
        if (i < 8192) {
            int col = i >> 7, k = i & 127;
            int q = col & 15, tc = col >> 4;
            int d = ((q & 7) << 3) + (q >> 3) + (tc << 1);
            WQTp[i] = (unsigned short)f2bf(WQ[k * 64 + d]);
            WKTp[i] = (unsigned short)f2bf(WK[k * 64 + d]);
            WVT[i]  = (unsigned short)f2bf(WV[k * 64 + col]);
        } else if (i < 8192 + 16384) {
            int j = i - 8192;
            int k4 = j >> 12, r = j & 4095;
            int col = r >> 6, kk = r & 63;
            WcT[j] = (unsigned short)f2bf(Wc[k4 * 4096 + kk * 64 + col]);
        } else if (i < 8192 + 16384 + 4096) {
            int j = i - 8192 - 16384;
            int col = j >> 6, kk = j & 63;
            WgT[j] = (unsigned short)f2bf(Wg[kk * 64 + col]);
        } else if (i < 8192 + 16384 + 4096 + 4096) {
            int j = i - 8192 - 16384 - 4096;
            int col = j >> 6, jj = j & 63;
            int q = col & 15, tc = col >> 4;
            int d = ((q & 7) << 3) + (q >> 3) + (tc << 1);
            WETb[j] = f2bf(WE[jj * 64 + d]);
        }
    } else {
        int i = (b - CB - PRB) * 256 + t;
        if (i < n * 64) {
            int node = i >> 6, j = i & 63;
            hpb[(size_t)node * 128 + j] = (unsigned short)f2bf(h[i]);
            hpb[(size_t)node * 128 + 64 + j] = (unsigned short)f2bf(p[i]);
        }
    }
}

__global__ void k_blocksum(const int* __restrict__ deg, int n, int* __restrict__ bsum) {
    __shared__ int s[256];
    int i = blockIdx.x * 256 + threadIdx.x;
    s[threadIdx.x] = (i < n) ? deg[i] : 0;
    __syncthreads();
    for (int off = 128; off > 0; off >>= 1) {
        if (threadIdx.x < off) s[threadIdx.x] += s[threadIdx.x + off];
        __syncthreads();
    }
    if (threadIdx.x == 0) bsum[blockIdx.x] = s[0];
}

__global__ void k_scan_bsum(int* __restrict__ bsum, int nb) {
    __shared__ int s[256];
    int t = threadIdx.x;
    int v = (t < nb) ? bsum[t] : 0;
    s[t] = v;
    __syncthreads();
    for (int off = 1; off < 256; off <<= 1) {
        int tmp = (t >= off) ? s[t - off] : 0;
        __syncthreads();
        s[t] += tmp;
        __syncthreads();
    }
    if (t < nb) bsum[t] = s[t] - v;  // exclusive
}

__global__ void k_scan_final(const int* __restrict__ deg, const int* __restrict__ bsum,
                             int n, int E, int* __restrict__ offsets,
                             int* __restrict__ cursor, float* __restrict__ dinv) {
    __shared__ int s[256];
    int t = threadIdx.x, i = blockIdx.x * 256 + t;
    int v = (i < n) ? deg[i] : 0;
    s[t] = v;
    __syncthreads();
    for (int off = 1; off < 256; off <<= 1) {
        int tmp = (t >= off) ? s[t - off] : 0;
        __syncthreads();
        s[t] += tmp;
        __syncthreads();
    }
    if (i < n) {
        int excl = s[t] - v + bsum[blockIdx.x];
        offsets[i] = excl;
        cursor[i] = excl;
        int dv = v < 1 ? 1 : v;
        dinv[i] = 1.0f / sqrtf((float)dv);
    }
    if (i == 0) offsets[n] = E;
}

// ---------- fused: payload scatter (+spos) || dst fill ----------
__global__ void fused_scatter(const int* __restrict__ dst, const int* __restrict__ src,
                              const float* __restrict__ ew, const float* __restrict__ dinv,
                              int E, int* __restrict__ cursor, int4* __restrict__ payload,
                              int* __restrict__ spos,
                              const int* __restrict__ offsets, int n, int* __restrict__ dsts,
                              int SCB) {
    int b = blockIdx.x, t = threadIdx.x;
    if (b < SCB) {
        int i = b * 256 + t;
        if (i < E) {
            int s = src[i], d = dst[i];
            int pcur = atomicAdd(&cursor[d], 1);
            int4 pl;
            pl.x = s;
            pl.y = __builtin_bit_cast(int, ew[i]);
            pl.z = __builtin_bit_cast(int, dinv[s]);
            pl.w = i;
            payload[pcur] = pl;
            spos[i] = pcur;
        }
    } else {
        int node = (b - SCB) * 256 + t;
        if (node < n) {
            int beg = offsets[node], end = offsets[node + 1];
            for (int e = beg; e < end; ++e) dsts[e] = node;
        }
    }
}

// ---------- fused: QKV MFMA || pass1 gathers ----------
__global__ __launch_bounds__(256) void fused_qp(
        const unsigned short* __restrict__ hpb,
        const unsigned short* __restrict__ WQTp, const unsigned short* __restrict__ WKTp,
        const unsigned short* __restrict__ WVT, int n,
        unsigned short* __restrict__ Qhb, unsigned short* __restrict__ Khb,
        unsigned short* __restrict__ Vhb,
        const int* __restrict__ offsets, const int4* __restrict__ payload,
        const float* __restrict__ dinv,
        unsigned short* __restrict__ Tx1b, unsigned short* __restrict__ aggb, int QB) {
    int t = threadIdx.x;
    if (blockIdx.x < QB) {
        // ---- k_qkv body ----
        int lane = t & 63;
        int q = lane & 15, g = lane >> 4;
        int wid = (blockIdx.x * 256 + t) >> 6;
        int nb16 = wid * 16;
        if (nb16 >= n) return;
        int node = nb16 + q;
        int nodec = node < n ? node : n - 1;

        f32x4 aq[4], ak[4], av[4];
#pragma unroll
        for (int tc = 0; tc < 4; ++tc) {
            aq[tc] = (f32x4){0, 0, 0, 0}; ak[tc] = (f32x4){0, 0, 0, 0}; av[tc] = (f32x4){0, 0, 0, 0};
        }
#pragma unroll
        for (int kk = 0; kk < 4; ++kk) {
            bf16x8 a = *(const bf16x8*)(hpb + (size_t)nodec * 128 + kk * 32 + g * 8);
#pragma unroll
            for (int tc = 0; tc < 4; ++tc) {
                bf16x8 bq = *(const bf16x8*)(WQTp + (tc * 16 + q) * 128 + kk * 32 + g * 8);
                bf16x8 bk = *(const bf16x8*)(WKTp + (tc * 16 + q) * 128 + kk * 32 + g * 8);
                bf16x8 bv = *(const bf16x8*)(WVT + (tc * 16 + q) * 128 + kk * 32 + g * 8);
                aq[tc] = __builtin_amdgcn_mfma_f32_16x16x32_bf16(a, bq, aq[tc], 0, 0, 0);
                ak[tc] = __builtin_amdgcn_mfma_f32_16x16x32_bf16(a, bk, ak[tc], 0, 0, 0);
                av[tc] = __builtin_amdgcn_mfma_f32_16x16x32_bf16(a, bv, av[tc], 0, 0, 0);
            }
        }
#pragma unroll
        for (int r = 0; r < 4; ++r) {
            int nd = nb16 + g * 4 + r;
            if (nd < n) {
                u16x4 oq, ok;
#pragma unroll
                for (int tc = 0; tc < 4; ++tc) {
                    oq[tc] = (unsigned short)f2bf(aq[tc][r]);
                    ok[tc] = (unsigned short)f2bf(ak[tc][r]);
                }
                *(u16x4*)(Qhb + (size_t)nd * 64 + q * 4) = oq;
                *(u16x4*)(Khb + (size_t)nd * 64 + q * 4) = ok;
#pragma unroll
                for (int tc = 0; tc < 4; ++tc)
                    Vhb[(size_t)nd * 64 + tc * 16 + q] = (unsigned short)f2bf(av[tc][r]);
            }
        }
    } else {
        // ---- k_pass1 body ----
        int w = t >> 6, lane = t & 63;
        int node = (blockIdx.x - QB) * 4 + w;
        if (node >= n) return;
        int q = lane & 7, g = lane >> 3;
        int beg = offsets[node], end = offsets[node + 1];
        float aL[8], aG[8];
#pragma unroll
        for (int c = 0; c < 8; ++c) { aL[c] = 0.f; aG[c] = 0.f; }
        int e2 = beg;
        for (; e2 + 16 <= end; e2 += 16) {
            int4 pa = payload[e2 + g], pb = payload[e2 + 8 + g];
            u16x8 va = *(const u16x8*)(hpb + (size_t)pa.x * 128 + q * 8);
            u16x8 vb = *(const u16x8*)(hpb + (size_t)pb.x * 128 + q * 8);
            float da = i2f(pa.z), db = i2f(pb.z);
            float wa = i2f(pa.y), wb = i2f(pb.y);
#pragma unroll
            for (int c = 0; c < 8; ++c) {
                float fa = bf2f(va[c]), fb = bf2f(vb[c]);
                aL[c] = fmaf(da, fa, aL[c]); aL[c] = fmaf(db, fb, aL[c]);
                aG[c] = fmaf(wa, fa, aG[c]); aG[c] = fmaf(wb, fb, aG[c]);
            }
        }
        for (; e2 < end; e2 += 8) {
            int e = e2 + g;
            if (e < end) {
                int4 pl = payload[e];
                u16x8 v = *(const u16x8*)(hpb + (size_t)pl.x * 128 + q * 8);
                float d = i2f(pl.z), wv = i2f(pl.y);
#pragma unroll
                for (int c = 0; c < 8; ++c) {
                    float f = bf2f(v[c]);
                    aL[c] = fmaf(d, f, aL[c]);
                    aG[c] = fmaf(wv, f, aG[c]);
                }
            }
        }
#pragma unroll
        for (int c = 0; c < 8; ++c) {
            aL[c] += __shfl_xor(aL[c], 8, 64);  aL[c] += __shfl_xor(aL[c], 16, 64);
            aL[c] += __shfl_xor(aL[c], 32, 64);
            aG[c] += __shfl_xor(aG[c], 8, 64);  aG[c] += __shfl_xor(aG[c], 16, 64);
            aG[c] += __shfl_xor(aG[c], 32, 64);
        }
        if (g == 0) {
            float dn = dinv[node];
            u16x8 o1, o2;
#pragma unroll
            for (int c = 0; c < 8; ++c) {
                o1[c] = (unsigned short)f2bf(-dn * aL[c]);
                o2[c] = (unsigned short)f2bf(aG[c]);
            }
            *(u16x8*)(Tx1b + (size_t)node * DD + q * 8) = o1;
            *(u16x8*)(aggb + (size_t)node * DD + q * 8) = o2;
        }
    }
}

// ---------- fused: EVERY block does its score slice (streaming), THEN its lap slice ----------
__global__ __launch_bounds__(256) void fused_sl(
        const float* __restrict__ efeat, const short* __restrict__ WETb,
        const int* __restrict__ esrc, const int* __restrict__ edst,
        const int* __restrict__ spos,
        const int4* __restrict__ payload,
        const unsigned short* __restrict__ Qhb, const unsigned short* __restrict__ Khb,
        int E, unsigned short* __restrict__ ssb,
        const int* __restrict__ offsets, const float* __restrict__ dinv,
        const unsigned short* __restrict__ Tx1b, const unsigned short* __restrict__ hpb,
        int n, unsigned short* __restrict__ Tx2b) {
    int t = threadIdx.x;
    // ================= phase 1: score (full machine, streaming e-rows) =================
    {
        int lane = t & 63;
        int q = lane & 15, g = lane >> 4;
        bf16x8 bfrag[2][4];
#pragma unroll
        for (int kc = 0; kc < 2; ++kc)
#pragma unroll
            for (int tc = 0; tc < 4; ++tc)
                bfrag[kc][tc] = *(const bf16x8*)(WETb + (tc * 16 + q) * 64 + kc * 32 + g * 8);

        const float invs = 0.35355339059327373f;  // 1/sqrt(8)
        int nwaves = gridDim.x * 4;
        int wid = (blockIdx.x * 256 + t) >> 6;
        int ntiles = (E + 15) >> 4;

        for (int wt = wid; wt < ntiles; wt += nwaves) {
            int ebase = wt * 16;
            int er = ebase + q;
            int erc = er < E ? er : E - 1;
            const float* ep = efeat + (size_t)erc * 64;   // sequential across tile
            float4 c0 = *(const float4*)(ep + g * 8);
            float4 c1 = *(const float4*)(ep + g * 8 + 4);
            float4 c2 = *(const float4*)(ep + 32 + g * 8);
            float4 c3 = *(const float4*)(ep + 32 + g * 8 + 4);

            u16x4 kv4[4], qv4[4];
            int sp[4];
#pragma unroll
            for (int r = 0; r < 4; ++r) {
                int e = ebase + g * 4 + r;
                int ec = e < E ? e : E - 1;
                sp[r] = spos[ec];
                kv4[r] = *(const u16x4*)(Khb + (size_t)esrc[ec] * 64 + q * 4);
                qv4[r] = *(const u16x4*)(Qhb + (size_t)edst[ec] * 64 + q * 4);
            }

            f32x4 acc0 = {0, 0, 0, 0}, acc1 = {0, 0, 0, 0};
            f32x4 acc2 = {0, 0, 0, 0}, acc3 = {0, 0, 0, 0};
            {
                bf16x8 a;
                a[0] = f2bf(c0.x); a[1] = f2bf(c0.y); a[2] = f2bf(c0.z); a[3] = f2bf(c0.w);
                a[4] = f2bf(c1.x); a[5] = f2bf(c1.y); a[6] = f2bf(c1.z); a[7] = f2bf(c1.w);
                acc0 = __builtin_amdgcn_mfma_f32_16x16x32_bf16(a, bfrag[0][0], acc0, 0, 0, 0);
                acc1 = __builtin_amdgcn_mfma_f32_16x16x32_bf16(a, bfrag[0][1], acc1, 0, 0, 0);
                acc2 = __builtin_amdgcn_mfma_f32_16x16x32_bf16(a, bfrag[0][2], acc2, 0, 0, 0);
                acc3 = __builtin_amdgcn_mfma_f32_16x16x32_bf16(a, bfrag[0][3], acc3, 0, 0, 0);
                a[0] = f2bf(c2.x); a[1] = f2bf(c2.y); a[2] = f2bf(c2.z); a[3] = f2bf(c2.w);
                a[4] = f2bf(c3.x); a[5] = f2bf(c3.y); a[6] = f2bf(c3.z); a[7] = f2bf(c3.w);
                acc0 = __builtin_amdgcn_mfma_f32_16x16x32_bf16(a, bfrag[1][0], acc0, 0, 0, 0);
                acc1 = __builtin_amdgcn_mfma_f32_16x16x32_bf16(a, bfrag[1][1], acc1, 0, 0, 0);
                acc2 = __builtin_amdgcn_mfma_f32_16x16x32_bf16(a, bfrag[1][2], acc2, 0, 0, 0);
                acc3 = __builtin_amdgcn_mfma_f32_16x16x32_bf16(a, bfrag[1][3], acc3, 0, 0, 0);
            }

#pragma unroll
            for (int r = 0; r < 4; ++r) {
                int e = ebase + g * 4 + r;
                float pv = bf2f(kv4[r][0]) * bf2f(qv4[r][0]) * acc0[r]
                         + bf2f(kv4[r][1]) * bf2f(qv4[r][1]) * acc1[r]
                         + bf2f(kv4[r][2]) * bf2f(qv4[r][2]) * acc2[r]
                         + bf2f(kv4[r][3]) * bf2f(qv4[r][3]) * acc3[r];
                pv *= invs;
                pv += __shfl_xor(pv, 8, 64);
                float sc = __expf(fminf(fmaxf(pv, -5.0f), 5.0f));
                if ((lane & 8) == 0 && e < E)
                    ssb[(size_t)sp[r] * HH + (q & 7)] = (unsigned short)f2bf(sc);
            }
        }
    }
    // ================= phase 2: lap Tx2 = 2*lap(Tx1) - h =================
    {
        int w = t >> 6, lane = t & 63;
        int node = blockIdx.x * 4 + w;
        if (node >= n) return;
        int q = lane & 7, g = lane >> 3;
        int beg = offsets[node], end = offsets[node + 1];
        float a[8];
#pragma unroll
        for (int c = 0; c < 8; ++c) a[c] = 0.f;
        int e2 = beg;
        for (; e2 + 16 <= end; e2 += 16) {
            int4 pa = payload[e2 + g], pb = payload[e2 + 8 + g];
            u16x8 va = *(const u16x8*)(Tx1b + (size_t)pa.x * 64 + q * 8);
            u16x8 vb = *(const u16x8*)(Tx1b + (size_t)pb.x * 64 + q * 8);
            float da = i2f(pa.z), db = i2f(pb.z);
#pragma unroll
            for (int c = 0; c < 8; ++c) {
                a[c] = fmaf(da, bf2f(va[c]), a[c]);
                a[c] = fmaf(db, bf2f(vb[c]), a[c]);
            }
        }
        for (; e2 < end; e2 += 8) {
            int e = e2 + g;
            if (e < end) {
                int4 pl = payload[e];
                u16x8 v = *(const u16x8*)(Tx1b + (size_t)pl.x * 64 + q * 8);
                float d = i2f(pl.z);
#pragma unroll
                for (int c = 0; c < 8; ++c) a[c] = fmaf(d, bf2f(v[c]), a[c]);
            }
        }
#pragma unroll
        for (int c = 0; c < 8; ++c) {
            a[c] += __shfl_xor(a[c], 8, 64);  a[c] += __shfl_xor(a[c], 16, 64);
            a[c] += __shfl_xor(a[c], 32, 64);
        }
        if (g == 0) {
            float dn = dinv[node];
            u16x8 pv = *(const u16x8*)(hpb + (size_t)node * 128 + q * 8);
            u16x8 o;
#pragma unroll
            for (int c = 0; c < 8; ++c) {
                float v = 2.0f * (-dn * a[c]) - bf2f(pv[c]);
                o[c] = (unsigned short)f2bf(v);
            }
            *(u16x8*)(Tx2b + (size_t)node * DD + q * 8) = o;
        }
    }
}

// ---------- fused: Tx3 = 2*lap(Tx2) - Tx1  AND  attention aggregation (ss bf16) ----------
__global__ void k_lap3_attn(const int* __restrict__ offsets, const int4* __restrict__ payload,
                            const float* __restrict__ dinv,
                            const unsigned short* __restrict__ Tx2b,
                            const unsigned short* __restrict__ Tx1b,
                            const unsigned short* __restrict__ Vhb,
                            const unsigned short* __restrict__ ssb,
                            int n, unsigned short* __restrict__ Tx3b,
                            float* __restrict__ out) {
    int w = threadIdx.x >> 6, lane = threadIdx.x & 63;
    int node = blockIdx.x * 4 + w;
    if (node >= n) return;
    int q = lane & 7, g = lane >> 3;  // head == q
    int beg = offsets[node], end = offsets[node + 1];
    float a[8], aV[8];
#pragma unroll
    for (int c = 0; c < 8; ++c) { a[c] = 0.f; aV[c] = 0.f; }
    float aZ = 0.f;
    int e2 = beg;
    for (; e2 + 16 <= end; e2 += 16) {
        int ea = e2 + g, eb = e2 + 8 + g;
        int4 pa = payload[ea], pb = payload[eb];
        u16x8 xa = *(const u16x8*)(Tx2b + (size_t)pa.x * DD + q * 8);
        u16x8 xb = *(const u16x8*)(Tx2b + (size_t)pb.x * DD + q * 8);
        u16x8 va = *(const u16x8*)(Vhb + (size_t)pa.x * DD + q * 8);
        u16x8 vb = *(const u16x8*)(Vhb + (size_t)pb.x * DD + q * 8);
        float sva = bf2f(ssb[(size_t)ea * HH + q]);
        float svb = bf2f(ssb[(size_t)eb * HH + q]);
        float da = i2f(pa.z), db = i2f(pb.z);
#pragma unroll
        for (int c = 0; c < 8; ++c) {
            a[c] = fmaf(da, bf2f(xa[c]), a[c]);
            a[c] = fmaf(db, bf2f(xb[c]), a[c]);
            aV[c] = fmaf(sva, bf2f(va[c]), aV[c]);
            aV[c] = fmaf(svb, bf2f(vb[c]), aV[c]);
        }
        aZ += sva + svb;
    }
    for (; e2 < end; e2 += 8) {
        int e = e2 + g;
        if (e < end) {
            int4 pl = payload[e];
            u16x8 x = *(const u16x8*)(Tx2b + (size_t)pl.x * DD + q * 8);
            u16x8 v = *(const u16x8*)(Vhb + (size_t)pl.x * DD + q * 8);
            float sv = bf2f(ssb[(size_t)e * HH + q]);
            float d = i2f(pl.z);
#pragma unroll
            for (int c = 0; c < 8; ++c) {
                a[c] = fmaf(d, bf2f(x[c]), a[c]);
                aV[c] = fmaf(sv, bf2f(v[c]), aV[c]);
            }
            aZ += sv;
        }
    }
#pragma unroll
    for (int c = 0; c < 8; ++c) {
        a[c] += __shfl_xor(a[c], 8, 64);   a[c] += __shfl_xor(a[c], 16, 64);
        a[c] += __shfl_xor(a[c], 32, 64);
        aV[c] += __shfl_xor(aV[c], 8, 64); aV[c] += __shfl_xor(aV[c], 16, 64);
        aV[c] += __shfl_xor(aV[c], 32, 64);
    }
    aZ += __shfl_xor(aZ, 8, 64); aZ += __shfl_xor(aZ, 16, 64); aZ += __shfl_xor(aZ, 32, 64);
    if (g == 0) {
        float dn = dinv[node];
        u16x8 pv = *(const u16x8*)(Tx1b + (size_t)node * DD + q * 8);
        u16x8 o;
        float inv = 1.0f / (aZ + 1e-6f);
        float4 o1, o2;
#pragma unroll
        for (int c = 0; c < 8; ++c) {
            float v = 2.0f * (-dn * a[c]) - bf2f(pv[c]);
            o[c] = (unsigned short)f2bf(v);
        }
        o1.x = aV[0] * inv; o1.y = aV[1] * inv; o1.z = aV[2] * inv; o1.w = aV[3] * inv;
        o2.x = aV[4] * inv; o2.y = aV[5] * inv; o2.z = aV[6] * inv; o2.w = aV[7] * inv;
        *(u16x8*)(Tx3b + (size_t)node * DD + q * 8) = o;
        *(float4*)(out + (size_t)node * 192 + 128 + q * 8) = o1;
        *(float4*)(out + (size_t)node * 192 + 128 + q * 8 + 4) = o2;
    }
}

// ---------- output via MFMA: cheb (4 fc-scaled tables) + gcn ----------
__global__ __launch_bounds__(256) void k_out(
        const unsigned short* __restrict__ hpb, const unsigned short* __restrict__ Tx1b,
        const unsigned short* __restrict__ Tx2b, const unsigned short* __restrict__ Tx3b,
        const unsigned short* __restrict__ aggb, const float* __restrict__ fc,
        const unsigned short* __restrict__ WcT, const unsigned short* __restrict__ WgT,
        const float* __restrict__ bc, const float* __restrict__ bg,
        int n, float* __restrict__ out) {
    int lane = threadIdx.x & 63;
    int q = lane & 15, g = lane >> 4;
    int wid = (blockIdx.x * 256 + threadIdx.x) >> 6;
    int nb16 = wid * 16;
    if (nb16 >= n) return;
    int node = nb16 + q;
    int nodec = node < n ? node : n - 1;
    float f0 = fc[nodec], f1 = fc[n + nodec], f2 = fc[2 * n + nodec], f3 = fc[3 * n + nodec];

    f32x4 ac[4], ag[4];
#pragma unroll
    for (int tc = 0; tc < 4; ++tc) { ac[tc] = (f32x4){0,0,0,0}; ag[tc] = (f32x4){0,0,0,0}; }

#pragma unroll
    for (int kk = 0; kk < 2; ++kk) {
        int off = kk * 32 + g * 8;
        bf16x8 a0r = *(const bf16x8*)(hpb + (size_t)nodec * 128 + off);   // Tx0 = h
        bf16x8 a1r = *(const bf16x8*)(Tx1b + (size_t)nodec * 64 + off);
        bf16x8 a2r = *(const bf16x8*)(Tx2b + (size_t)nodec * 64 + off);
        bf16x8 a3r = *(const bf16x8*)(Tx3b + (size_t)nodec * 64 + off);
        bf16x8 aA  = *(const bf16x8*)(aggb + (size_t)nodec * 64 + off);
        bf16x8 a0, a1, a2, a3;
#pragma unroll
        for (int j = 0; j < 8; ++j) {
            a0[j] = f2bf(f0 * bf2f((unsigned short)a0r[j]));
            a1[j] = f2bf(f1 * bf2f((unsigned short)a1r[j]));
            a2[j] = f2bf(f2 * bf2f((unsigned short)a2r[j]));
            a3[j] = f2bf(f3 * bf2f((unsigned short)a3r[j]));
        }
#pragma unroll
        for (int tc = 0; tc < 4; ++tc) {
            bf16x8 b0 = *(const bf16x8*)(WcT + 0 * 4096 + (tc * 16 + q) * 64 + off);
            bf16x8 b1 = *(const bf16x8*)(WcT + 1 * 4096 + (tc * 16 + q) * 64 + off);
            bf16x8 b2 = *(const bf16x8*)(WcT + 2 * 4096 + (tc * 16 + q) * 64 + off);
            bf16x8 b3 = *(const bf16x8*)(WcT + 3 * 4096 + (tc * 16 + q) * 64 + off);
            bf16x8 bgw = *(const bf16x8*)(WgT + (tc * 16 + q) * 64 + off);
            ac[tc] = __builtin_amdgcn_mfma_f32_16x16x32_bf16(a0, b0, ac[tc], 0, 0, 0);
            ac[tc] = __builtin_amdgcn_mfma_f32_16x16x32_bf16(a1, b1, ac[tc], 0, 0, 0);
            ac[tc] = __builtin_amdgcn_mfma_f32_16x16x32_bf16(a2, b2, ac[tc], 0, 0, 0);
            ac[tc] = __builtin_amdgcn_mfma_f32_16x16x32_bf16(a3, b3, ac[tc], 0, 0, 0);
            ag[tc] = __builtin_amdgcn_mfma_f32_16x16x32_bf16(aA, bgw, ag[tc], 0, 0, 0);
        }
    }
#pragma unroll
    for (int tc = 0; tc < 4; ++tc) {
        float bcv = bc[tc * 16 + q], bgv = bg[tc * 16 + q];
#pragma unroll
        for (int r = 0; r < 4; ++r) {
            int nd = nb16 + g * 4 + r;
            if (nd < n) {
                out[(size_t)nd * 192 + tc * 16 + q] = ac[tc][r] + bcv;
                out[(size_t)nd * 192 + 64 + tc * 16 + q] = ag[tc][r] + bgv;
            }
        }
    }
}

extern "C" void kernel_launch(void* const* d_in, const int* in_sizes, int n_in,
                              void* d_out, int out_size, void* d_ws, size_t ws_size,
                              hipStream_t stream) {
    const float* h  = (const float*)d_in[0];
    const float* p  = (const float*)d_in[1];
    const float* ef = (const float*)d_in[2];
    const float* ew = (const float*)d_in[3];
    const float* fc = (const float*)d_in[4];
    const int* esrc = (const int*)d_in[5];
    const int* edst = (const int*)d_in[6];
    const float* Wc = (const float*)d_in[7];
    const float* bc = (const float*)d_in[8];
    const float* Wg = (const float*)d_in[9];
    const float* bg = (const float*)d_in[10];
    const float* WQ = (const float*)d_in[11];
    const float* WK = (const float*)d_in[12];
    const float* WV = (const float*)d_in[13];
    const float* WE = (const float*)d_in[14];

    const int n = in_sizes[0] / DD;   // 50000
    const int E = in_sizes[5];        // 800000
    float* out = (float*)d_out;

    char* wsp = (char*)d_ws;
    size_t o = 0;
    auto alloc = [&](size_t bytes) -> void* {
        void* r = (void*)(wsp + o);
        o = (o + bytes + 255) & ~(size_t)255;
        return r;
    };
    int* deg     = (int*)alloc((size_t)n * 4);
    int* offsets = (int*)alloc((size_t)(n + 1) * 4);
    int* cursor  = (int*)alloc((size_t)n * 4);
    int4* payload = (int4*)alloc((size_t)E * 16);
    int* spos    = (int*)alloc((size_t)E * 4);
    int* dsts    = (int*)alloc((size_t)E * 4);
    int* bsum    = (int*)alloc(1024 * 4);
    float* dinv  = (float*)alloc((size_t)n * 4);
    short* WETb  = (short*)alloc(4096 * 2);
    unsigned short* WQTp = (unsigned short*)alloc(8192 * 2);
    unsigned short* WKTp = (unsigned short*)alloc(8192 * 2);
    unsigned short* WVT  = (unsigned short*)alloc(8192 * 2);
    unsigned short* WcT  = (unsigned short*)alloc(16384 * 2);
    unsigned short* WgT  = (unsigned short*)alloc(4096 * 2);
    unsigned short* hpb  = (unsigned short*)alloc((size_t)n * 128 * 2);
    unsigned short* Tx1b = (unsigned short*)alloc((size_t)n * DD * 2);
    unsigned short* Tx2b = (unsigned short*)alloc((size_t)n * DD * 2);
    unsigned short* Tx3b = (unsigned short*)alloc((size_t)n * DD * 2);
    unsigned short* aggb = (unsigned short*)alloc((size_t)n * DD * 2);
    unsigned short* Vhb  = (unsigned short*)alloc((size_t)n * DD * 2);
    unsigned short* Qhb  = (unsigned short*)alloc((size_t)n * DD * 2);
    unsigned short* Khb  = (unsigned short*)alloc((size_t)n * DD * 2);
    unsigned short* ssb  = (unsigned short*)alloc((size_t)E * HH * 2);
    (void)ws_size; (void)n_in; (void)out_size;

    hipMemsetAsync(deg, 0, (size_t)n * 4, stream);

    int nb = (n + 255) / 256;
    int CB = (E + 255) / 256;                 // count blocks
    int PRB = 128;                            // prep blocks (32768/256)
    int HB = (n * 64 + 255) / 256;            // hpb blocks
    fused_init<<<CB + PRB + HB, 256, 0, stream>>>(edst, E, deg, WQ, WK, WV, Wc, Wg, WE,
                                                  WQTp, WKTp, WVT, WcT, WgT, WETb,
                                                  h, p, n, hpb, CB, PRB);
    k_blocksum<<<nb, 256, 0, stream>>>(deg, n, bsum);
    k_scan_bsum<<<1, 256, 0, stream>>>(bsum, nb);
    k_scan_final<<<nb, 256, 0, stream>>>(deg, bsum, n, E, offsets, cursor, dinv);

    int SCB = (E + 255) / 256;
    fused_scatter<<<SCB + nb, 256, 0, stream>>>(edst, esrc, ew, dinv, E, cursor, payload,
                                                spos, offsets, n, dsts, SCB);

    int qkv_waves = (n + 15) / 16;
    int QB = (qkv_waves + 3) / 4;
    int PB = (n + 3) / 4;
    fused_qp<<<QB + PB, 256, 0, stream>>>(hpb, WQTp, WKTp, WVT, n, Qhb, Khb, Vhb,
                                          offsets, payload, dinv, Tx1b, aggb, QB);

    int LB = (n + 3) / 4;   // every block: score slice then lap slice
    fused_sl<<<LB, 256, 0, stream>>>(ef, WETb, esrc, edst, spos, payload, Qhb, Khb,
                                     E, ssb, offsets, dinv, Tx1b, hpb, n, Tx2b);

    k_lap3_attn<<<(n + 3) / 4, 256, 0, stream>>>(offsets, payload, dinv, Tx2b, Tx1b, Vhb,
                                                 ssb, n, Tx3b, out);

    int out_waves = (n + 15) / 16;
    k_out<<<(out_waves + 3) / 4, 256, 0, stream>>>(hpb, Tx1b, Tx2b, Tx3b, aggb, fc,
                                                   WcT, WgT, bc, bg, n, out);
}

// Round 17
// 331.862 us; speedup vs baseline: 1.0591x; 1.0591x over previous
//
#include <hip/hip_runtime.h>
#include <math.h>

#define DD 64
#define HH 8
#define KORD 4

typedef __attribute__((ext_vector_type(8))) short bf16x8;
typedef __attribute__((ext_vector_type(4))) float f32x4;
typedef __attribute__((ext_vector_type(8))) unsigned short u16x8;
typedef __attribute__((ext_vector_type(4))) unsigned short u16x4;

__device__ __forceinline__ short f2bf(float f) {
    unsigned u = __builtin_bit_cast(unsigned, f);
    u = (u + 0x7fffu + ((u >> 16) & 1u)) >> 16;
    return (short)u;
}
__device__ __forceinline__ float bf2f(unsigned short u) {
    unsigned x = ((unsigned)u) << 16;
    return __builtin_bit_cast(float, x);
}
__device__ __forceinline__ float i2f(int v) { return __builtin_bit_cast(float, v); }

// ---------- fused: edge-count || weight-prep || hp bf16 cast ----------
__global__ void fused_init(const int* __restrict__ dst, int E, int* __restrict__ deg,
                           const float* __restrict__ WQ, const float* __restrict__ WK,
                           const float* __restrict__ WV, const float* __restrict__ Wc,
                           const float* __restrict__ Wg, const float* __restrict__ WE,
                           unsigned short* __restrict__ WQTp, unsigned short* __restrict__ WKTp,
                           unsigned short* __restrict__ WVT, unsigned short* __restrict__ WcT,
                           unsigned short* __restrict__ WgT, short* __restrict__ WETb,
                           const float* __restrict__ h, const float* __restrict__ p,
                           int n, unsigned short* __restrict__ hpb, int CB, int PRB) {
    int b = blockIdx.x, t = threadIdx.x;
    if (b < CB) {
        int i = b * 256 + t;
        if (i < E) atomicAdd(&deg[dst[i]], 1);
    } else if (b < CB + PRB) {
        int i = (b - CB) * 256 + t;
        if (i < 8192) {
            int col = i >> 7, k = i & 127;
            int q = col & 15, tc = col >> 4;
            int d = ((q & 7) << 3) + (q >> 3) + (tc << 1);
            WQTp[i] = (unsigned short)f2bf(WQ[k * 64 + d]);
            WKTp[i] = (unsigned short)f2bf(WK[k * 64 + d]);
            WVT[i]  = (unsigned short)f2bf(WV[k * 64 + col]);
        } else if (i < 8192 + 16384) {
            int j = i - 8192;
            int k4 = j >> 12, r = j & 4095;
            int col = r >> 6, kk = r & 63;
            WcT[j] = (unsigned short)f2bf(Wc[k4 * 4096 + kk * 64 + col]);
        } else if (i < 8192 + 16384 + 4096) {
            int j = i - 8192 - 16384;
            int col = j >> 6, kk = j & 63;
            WgT[j] = (unsigned short)f2bf(Wg[kk * 64 + col]);
        } else if (i < 8192 + 16384 + 4096 + 4096) {
            int j = i - 8192 - 16384 - 4096;
            int col = j >> 6, jj = j & 63;
            int q = col & 15, tc = col >> 4;
            int d = ((q & 7) << 3) + (q >> 3) + (tc << 1);
            WETb[j] = f2bf(WE[jj * 64 + d]);
        }
    } else {
        int i = (b - CB - PRB) * 256 + t;
        if (i < n * 64) {
            int node = i >> 6, j = i & 63;
            hpb[(size_t)node * 128 + j] = (unsigned short)f2bf(h[i]);
            hpb[(size_t)node * 128 + 64 + j] = (unsigned short)f2bf(p[i]);
        }
    }
}

__global__ void k_blocksum(const int* __restrict__ deg, int n, int* __restrict__ bsum) {
    __shared__ int s[256];
    int i = blockIdx.x * 256 + threadIdx.x;
    s[threadIdx.x] = (i < n) ? deg[i] : 0;
    __syncthreads();
    for (int off = 128; off > 0; off >>= 1) {
        if (threadIdx.x < off) s[threadIdx.x] += s[threadIdx.x + off];
        __syncthreads();
    }
    if (threadIdx.x == 0) bsum[blockIdx.x] = s[0];
}

__global__ void k_scan_bsum(int* __restrict__ bsum, int nb) {
    __shared__ int s[256];
    int t = threadIdx.x;
    int v = (t < nb) ? bsum[t] : 0;
    s[t] = v;
    __syncthreads();
    for (int off = 1; off < 256; off <<= 1) {
        int tmp = (t >= off) ? s[t - off] : 0;
        __syncthreads();
        s[t] += tmp;
        __syncthreads();
    }
    if (t < nb) bsum[t] = s[t] - v;  // exclusive
}

__global__ void k_scan_final(const int* __restrict__ deg, const int* __restrict__ bsum,
                             int n, int E, int* __restrict__ offsets,
                             int* __restrict__ cursor, float* __restrict__ dinv) {
    __shared__ int s[256];
    int t = threadIdx.x, i = blockIdx.x * 256 + t;
    int v = (i < n) ? deg[i] : 0;
    s[t] = v;
    __syncthreads();
    for (int off = 1; off < 256; off <<= 1) {
        int tmp = (t >= off) ? s[t - off] : 0;
        __syncthreads();
        s[t] += tmp;
        __syncthreads();
    }
    if (i < n) {
        int excl = s[t] - v + bsum[blockIdx.x];
        offsets[i] = excl;
        cursor[i] = excl;
        int dv = v < 1 ? 1 : v;
        dinv[i] = 1.0f / sqrtf((float)dv);
    }
    if (i == 0) offsets[n] = E;
}

// ---------- fused: payload scatter (+spos) || dst fill ----------
__global__ void fused_scatter(const int* __restrict__ dst, const int* __restrict__ src,
                              const float* __restrict__ ew, const float* __restrict__ dinv,
                              int E, int* __restrict__ cursor, int4* __restrict__ payload,
                              int* __restrict__ spos,
                              const int* __restrict__ offsets, int n, int* __restrict__ dsts,
                              int SCB) {
    int b = blockIdx.x, t = threadIdx.x;
    if (b < SCB) {
        int i = b * 256 + t;
        if (i < E) {
            int s = src[i], d = dst[i];
            int pcur = atomicAdd(&cursor[d], 1);
            int4 pl;
            pl.x = s;
            pl.y = __builtin_bit_cast(int, ew[i]);
            pl.z = __builtin_bit_cast(int, dinv[s]);
            pl.w = i;
            payload[pcur] = pl;
            spos[i] = pcur;
        }
    } else {
        int node = (b - SCB) * 256 + t;
        if (node < n) {
            int beg = offsets[node], end = offsets[node + 1];
            for (int e = beg; e < end; ++e) dsts[e] = node;
        }
    }
}

// ---------- fused: QKV MFMA || pass1 gathers ----------
__global__ __launch_bounds__(256) void fused_qp(
        const unsigned short* __restrict__ hpb,
        const unsigned short* __restrict__ WQTp, const unsigned short* __restrict__ WKTp,
        const unsigned short* __restrict__ WVT, int n,
        unsigned short* __restrict__ Qhb, unsigned short* __restrict__ Khb,
        unsigned short* __restrict__ Vhb,
        const int* __restrict__ offsets, const int4* __restrict__ payload,
        const float* __restrict__ dinv,
        unsigned short* __restrict__ Tx1b, unsigned short* __restrict__ aggb, int QB) {
    int t = threadIdx.x;
    if (blockIdx.x < QB) {
        // ---- k_qkv body ----
        int lane = t & 63;
        int q = lane & 15, g = lane >> 4;
        int wid = (blockIdx.x * 256 + t) >> 6;
        int nb16 = wid * 16;
        if (nb16 >= n) return;
        int node = nb16 + q;
        int nodec = node < n ? node : n - 1;

        f32x4 aq[4], ak[4], av[4];
#pragma unroll
        for (int tc = 0; tc < 4; ++tc) {
            aq[tc] = (f32x4){0, 0, 0, 0}; ak[tc] = (f32x4){0, 0, 0, 0}; av[tc] = (f32x4){0, 0, 0, 0};
        }
#pragma unroll
        for (int kk = 0; kk < 4; ++kk) {
            bf16x8 a = *(const bf16x8*)(hpb + (size_t)nodec * 128 + kk * 32 + g * 8);
#pragma unroll
            for (int tc = 0; tc < 4; ++tc) {
                bf16x8 bq = *(const bf16x8*)(WQTp + (tc * 16 + q) * 128 + kk * 32 + g * 8);
                bf16x8 bk = *(const bf16x8*)(WKTp + (tc * 16 + q) * 128 + kk * 32 + g * 8);
                bf16x8 bv = *(const bf16x8*)(WVT + (tc * 16 + q) * 128 + kk * 32 + g * 8);
                aq[tc] = __builtin_amdgcn_mfma_f32_16x16x32_bf16(a, bq, aq[tc], 0, 0, 0);
                ak[tc] = __builtin_amdgcn_mfma_f32_16x16x32_bf16(a, bk, ak[tc], 0, 0, 0);
                av[tc] = __builtin_amdgcn_mfma_f32_16x16x32_bf16(a, bv, av[tc], 0, 0, 0);
            }
        }
#pragma unroll
        for (int r = 0; r < 4; ++r) {
            int nd = nb16 + g * 4 + r;
            if (nd < n) {
                u16x4 oq, ok;
#pragma unroll
                for (int tc = 0; tc < 4; ++tc) {
                    oq[tc] = (unsigned short)f2bf(aq[tc][r]);
                    ok[tc] = (unsigned short)f2bf(ak[tc][r]);
                }
                *(u16x4*)(Qhb + (size_t)nd * 64 + q * 4) = oq;
                *(u16x4*)(Khb + (size_t)nd * 64 + q * 4) = ok;
#pragma unroll
                for (int tc = 0; tc < 4; ++tc)
                    Vhb[(size_t)nd * 64 + tc * 16 + q] = (unsigned short)f2bf(av[tc][r]);
            }
        }
    } else {
        // ---- k_pass1 body ----
        int w = t >> 6, lane = t & 63;
        int node = (blockIdx.x - QB) * 4 + w;
        if (node >= n) return;
        int q = lane & 7, g = lane >> 3;
        int beg = offsets[node], end = offsets[node + 1];
        float aL[8], aG[8];
#pragma unroll
        for (int c = 0; c < 8; ++c) { aL[c] = 0.f; aG[c] = 0.f; }
        int e2 = beg;
        for (; e2 + 16 <= end; e2 += 16) {
            int4 pa = payload[e2 + g], pb = payload[e2 + 8 + g];
            u16x8 va = *(const u16x8*)(hpb + (size_t)pa.x * 128 + q * 8);
            u16x8 vb = *(const u16x8*)(hpb + (size_t)pb.x * 128 + q * 8);
            float da = i2f(pa.z), db = i2f(pb.z);
            float wa = i2f(pa.y), wb = i2f(pb.y);
#pragma unroll
            for (int c = 0; c < 8; ++c) {
                float fa = bf2f(va[c]), fb = bf2f(vb[c]);
                aL[c] = fmaf(da, fa, aL[c]); aL[c] = fmaf(db, fb, aL[c]);
                aG[c] = fmaf(wa, fa, aG[c]); aG[c] = fmaf(wb, fb, aG[c]);
            }
        }
        for (; e2 < end; e2 += 8) {
            int e = e2 + g;
            if (e < end) {
                int4 pl = payload[e];
                u16x8 v = *(const u16x8*)(hpb + (size_t)pl.x * 128 + q * 8);
                float d = i2f(pl.z), wv = i2f(pl.y);
#pragma unroll
                for (int c = 0; c < 8; ++c) {
                    float f = bf2f(v[c]);
                    aL[c] = fmaf(d, f, aL[c]);
                    aG[c] = fmaf(wv, f, aG[c]);
                }
            }
        }
#pragma unroll
        for (int c = 0; c < 8; ++c) {
            aL[c] += __shfl_xor(aL[c], 8, 64);  aL[c] += __shfl_xor(aL[c], 16, 64);
            aL[c] += __shfl_xor(aL[c], 32, 64);
            aG[c] += __shfl_xor(aG[c], 8, 64);  aG[c] += __shfl_xor(aG[c], 16, 64);
            aG[c] += __shfl_xor(aG[c], 32, 64);
        }
        if (g == 0) {
            float dn = dinv[node];
            u16x8 o1, o2;
#pragma unroll
            for (int c = 0; c < 8; ++c) {
                o1[c] = (unsigned short)f2bf(-dn * aL[c]);
                o2[c] = (unsigned short)f2bf(aG[c]);
            }
            *(u16x8*)(Tx1b + (size_t)node * DD + q * 8) = o1;
            *(u16x8*)(aggb + (size_t)node * DD + q * 8) = o2;
        }
    }
}

// ---------- fused: score (original-order coalesced e-stream) || lap(Tx1->Tx2) ----------
__global__ __launch_bounds__(256) void fused_sl(
        const float* __restrict__ efeat, const short* __restrict__ WETb,
        const int* __restrict__ esrc, const int* __restrict__ edst,
        const int* __restrict__ spos,
        const int4* __restrict__ payload,
        const unsigned short* __restrict__ Qhb, const unsigned short* __restrict__ Khb,
        int E, unsigned short* __restrict__ ssb,
        const int* __restrict__ offsets, const float* __restrict__ dinv,
        const unsigned short* __restrict__ Tx1b, const unsigned short* __restrict__ hpb,
        int n, unsigned short* __restrict__ Tx2b, int SB, int score_nwaves) {
    int t = threadIdx.x;
    if (blockIdx.x < SB) {
        // ---- score: original edge order, coalesced e-stream ----
        int lane = t & 63;
        int q = lane & 15, g = lane >> 4;
        bf16x8 bfrag[2][4];
#pragma unroll
        for (int kc = 0; kc < 2; ++kc)
#pragma unroll
            for (int tc = 0; tc < 4; ++tc)
                bfrag[kc][tc] = *(const bf16x8*)(WETb + (tc * 16 + q) * 64 + kc * 32 + g * 8);

        const float invs = 0.35355339059327373f;  // 1/sqrt(8)
        int wid = (blockIdx.x * 256 + t) >> 6;
        int ntiles = (E + 15) >> 4;

        for (int wt = wid; wt < ntiles; wt += score_nwaves) {
            int ebase = wt * 16;
            int er = ebase + q;
            int erc = er < E ? er : E - 1;
            const float* ep = efeat + (size_t)erc * 64;   // sequential across tile
            float4 c0 = *(const float4*)(ep + g * 8);
            float4 c1 = *(const float4*)(ep + g * 8 + 4);
            float4 c2 = *(const float4*)(ep + 32 + g * 8);
            float4 c3 = *(const float4*)(ep + 32 + g * 8 + 4);

            u16x4 kv4[4], qv4[4];
            int sp[4];
#pragma unroll
            for (int r = 0; r < 4; ++r) {
                int e = ebase + g * 4 + r;
                int ec = e < E ? e : E - 1;
                int sA = esrc[ec], tA = edst[ec];
                sp[r] = spos[ec];
                kv4[r] = *(const u16x4*)(Khb + (size_t)sA * 64 + q * 4);
                qv4[r] = *(const u16x4*)(Qhb + (size_t)tA * 64 + q * 4);
            }

            f32x4 acc0 = {0, 0, 0, 0}, acc1 = {0, 0, 0, 0};
            f32x4 acc2 = {0, 0, 0, 0}, acc3 = {0, 0, 0, 0};
            {
                bf16x8 a;
                a[0] = f2bf(c0.x); a[1] = f2bf(c0.y); a[2] = f2bf(c0.z); a[3] = f2bf(c0.w);
                a[4] = f2bf(c1.x); a[5] = f2bf(c1.y); a[6] = f2bf(c1.z); a[7] = f2bf(c1.w);
                acc0 = __builtin_amdgcn_mfma_f32_16x16x32_bf16(a, bfrag[0][0], acc0, 0, 0, 0);
                acc1 = __builtin_amdgcn_mfma_f32_16x16x32_bf16(a, bfrag[0][1], acc1, 0, 0, 0);
                acc2 = __builtin_amdgcn_mfma_f32_16x16x32_bf16(a, bfrag[0][2], acc2, 0, 0, 0);
                acc3 = __builtin_amdgcn_mfma_f32_16x16x32_bf16(a, bfrag[0][3], acc3, 0, 0, 0);
                a[0] = f2bf(c2.x); a[1] = f2bf(c2.y); a[2] = f2bf(c2.z); a[3] = f2bf(c2.w);
                a[4] = f2bf(c3.x); a[5] = f2bf(c3.y); a[6] = f2bf(c3.z); a[7] = f2bf(c3.w);
                acc0 = __builtin_amdgcn_mfma_f32_16x16x32_bf16(a, bfrag[1][0], acc0, 0, 0, 0);
                acc1 = __builtin_amdgcn_mfma_f32_16x16x32_bf16(a, bfrag[1][1], acc1, 0, 0, 0);
                acc2 = __builtin_amdgcn_mfma_f32_16x16x32_bf16(a, bfrag[1][2], acc2, 0, 0, 0);
                acc3 = __builtin_amdgcn_mfma_f32_16x16x32_bf16(a, bfrag[1][3], acc3, 0, 0, 0);
            }

#pragma unroll
            for (int r = 0; r < 4; ++r) {
                int e = ebase + g * 4 + r;
                float pv = bf2f(kv4[r][0]) * bf2f(qv4[r][0]) * acc0[r]
                         + bf2f(kv4[r][1]) * bf2f(qv4[r][1]) * acc1[r]
                         + bf2f(kv4[r][2]) * bf2f(qv4[r][2]) * acc2[r]
                         + bf2f(kv4[r][3]) * bf2f(qv4[r][3]) * acc3[r];
                pv *= invs;
                pv += __shfl_xor(pv, 8, 64);
                float sc = __expf(fminf(fmaxf(pv, -5.0f), 5.0f));
                if ((lane & 8) == 0 && e < E)
                    ssb[(size_t)sp[r] * HH + (q & 7)] = (unsigned short)f2bf(sc);
            }
        }
    } else {
        // ---- lap: Tx2 = 2*lap(Tx1) - h ----
        int w = t >> 6, lane = t & 63;
        int node = (blockIdx.x - SB) * 4 + w;
        if (node >= n) return;
        int q = lane & 7, g = lane >> 3;
        int beg = offsets[node], end = offsets[node + 1];
        float a[8];
#pragma unroll
        for (int c = 0; c < 8; ++c) a[c] = 0.f;
        int e2 = beg;
        for (; e2 + 16 <= end; e2 += 16) {
            int4 pa = payload[e2 + g], pb = payload[e2 + 8 + g];
            u16x8 va = *(const u16x8*)(Tx1b + (size_t)pa.x * 64 + q * 8);
            u16x8 vb = *(const u16x8*)(Tx1b + (size_t)pb.x * 64 + q * 8);
            float da = i2f(pa.z), db = i2f(pb.z);
#pragma unroll
            for (int c = 0; c < 8; ++c) {
                a[c] = fmaf(da, bf2f(va[c]), a[c]);
                a[c] = fmaf(db, bf2f(vb[c]), a[c]);
            }
        }
        for (; e2 < end; e2 += 8) {
            int e = e2 + g;
            if (e < end) {
                int4 pl = payload[e];
                u16x8 v = *(const u16x8*)(Tx1b + (size_t)pl.x * 64 + q * 8);
                float d = i2f(pl.z);
#pragma unroll
                for (int c = 0; c < 8; ++c) a[c] = fmaf(d, bf2f(v[c]), a[c]);
            }
        }
#pragma unroll
        for (int c = 0; c < 8; ++c) {
            a[c] += __shfl_xor(a[c], 8, 64);  a[c] += __shfl_xor(a[c], 16, 64);
            a[c] += __shfl_xor(a[c], 32, 64);
        }
        if (g == 0) {
            float dn = dinv[node];
            u16x8 pv = *(const u16x8*)(hpb + (size_t)node * 128 + q * 8);
            u16x8 o;
#pragma unroll
            for (int c = 0; c < 8; ++c) {
                float v = 2.0f * (-dn * a[c]) - bf2f(pv[c]);
                o[c] = (unsigned short)f2bf(v);
            }
            *(u16x8*)(Tx2b + (size_t)node * DD + q * 8) = o;
        }
    }
}

// ---------- fused: Tx3 = 2*lap(Tx2) - Tx1  AND  attention aggregation (ss bf16) ----------
__global__ void k_lap3_attn(const int* __restrict__ offsets, const int4* __restrict__ payload,
                            const float* __restrict__ dinv,
                            const unsigned short* __restrict__ Tx2b,
                            const unsigned short* __restrict__ Tx1b,
                            const unsigned short* __restrict__ Vhb,
                            const unsigned short* __restrict__ ssb,
                            int n, unsigned short* __restrict__ Tx3b,
                            float* __restrict__ out) {
    int w = threadIdx.x >> 6, lane = threadIdx.x & 63;
    int node = blockIdx.x * 4 + w;
    if (node >= n) return;
    int q = lane & 7, g = lane >> 3;  // head == q
    int beg = offsets[node], end = offsets[node + 1];
    float a[8], aV[8];
#pragma unroll
    for (int c = 0; c < 8; ++c) { a[c] = 0.f; aV[c] = 0.f; }
    float aZ = 0.f;
    int e2 = beg;
    for (; e2 + 16 <= end; e2 += 16) {
        int ea = e2 + g, eb = e2 + 8 + g;
        int4 pa = payload[ea], pb = payload[eb];
        u16x8 xa = *(const u16x8*)(Tx2b + (size_t)pa.x * DD + q * 8);
        u16x8 xb = *(const u16x8*)(Tx2b + (size_t)pb.x * DD + q * 8);
        u16x8 va = *(const u16x8*)(Vhb + (size_t)pa.x * DD + q * 8);
        u16x8 vb = *(const u16x8*)(Vhb + (size_t)pb.x * DD + q * 8);
        float sva = bf2f(ssb[(size_t)ea * HH + q]);
        float svb = bf2f(ssb[(size_t)eb * HH + q]);
        float da = i2f(pa.z), db = i2f(pb.z);
#pragma unroll
        for (int c = 0; c < 8; ++c) {
            a[c] = fmaf(da, bf2f(xa[c]), a[c]);
            a[c] = fmaf(db, bf2f(xb[c]), a[c]);
            aV[c] = fmaf(sva, bf2f(va[c]), aV[c]);
            aV[c] = fmaf(svb, bf2f(vb[c]), aV[c]);
        }
        aZ += sva + svb;
    }
    for (; e2 < end; e2 += 8) {
        int e = e2 + g;
        if (e < end) {
            int4 pl = payload[e];
            u16x8 x = *(const u16x8*)(Tx2b + (size_t)pl.x * DD + q * 8);
            u16x8 v = *(const u16x8*)(Vhb + (size_t)pl.x * DD + q * 8);
            float sv = bf2f(ssb[(size_t)e * HH + q]);
            float d = i2f(pl.z);
#pragma unroll
            for (int c = 0; c < 8; ++c) {
                a[c] = fmaf(d, bf2f(x[c]), a[c]);
                aV[c] = fmaf(sv, bf2f(v[c]), aV[c]);
            }
            aZ += sv;
        }
    }
#pragma unroll
    for (int c = 0; c < 8; ++c) {
        a[c] += __shfl_xor(a[c], 8, 64);   a[c] += __shfl_xor(a[c], 16, 64);
        a[c] += __shfl_xor(a[c], 32, 64);
        aV[c] += __shfl_xor(aV[c], 8, 64); aV[c] += __shfl_xor(aV[c], 16, 64);
        aV[c] += __shfl_xor(aV[c], 32, 64);
    }
    aZ += __shfl_xor(aZ, 8, 64); aZ += __shfl_xor(aZ, 16, 64); aZ += __shfl_xor(aZ, 32, 64);
    if (g == 0) {
        float dn = dinv[node];
        u16x8 pv = *(const u16x8*)(Tx1b + (size_t)node * DD + q * 8);
        u16x8 o;
        float inv = 1.0f / (aZ + 1e-6f);
        float4 o1, o2;
#pragma unroll
        for (int c = 0; c < 8; ++c) {
            float v = 2.0f * (-dn * a[c]) - bf2f(pv[c]);
            o[c] = (unsigned short)f2bf(v);
        }
        o1.x = aV[0] * inv; o1.y = aV[1] * inv; o1.z = aV[2] * inv; o1.w = aV[3] * inv;
        o2.x = aV[4] * inv; o2.y = aV[5] * inv; o2.z = aV[6] * inv; o2.w = aV[7] * inv;
        *(u16x8*)(Tx3b + (size_t)node * DD + q * 8) = o;
        *(float4*)(out + (size_t)node * 192 + 128 + q * 8) = o1;
        *(float4*)(out + (size_t)node * 192 + 128 + q * 8 + 4) = o2;
    }
}

// ---------- output via MFMA: cheb (4 fc-scaled tables) + gcn ----------
__global__ __launch_bounds__(256) void k_out(
        const unsigned short* __restrict__ hpb, const unsigned short* __restrict__ Tx1b,
        const unsigned short* __restrict__ Tx2b, const unsigned short* __restrict__ Tx3b,
        const unsigned short* __restrict__ aggb, const float* __restrict__ fc,
        const unsigned short* __restrict__ WcT, const unsigned short* __restrict__ WgT,
        const float* __restrict__ bc, const float* __restrict__ bg,
        int n, float* __restrict__ out) {
    int lane = threadIdx.x & 63;
    int q = lane & 15, g = lane >> 4;
    int wid = (blockIdx.x * 256 + threadIdx.x) >> 6;
    int nb16 = wid * 16;
    if (nb16 >= n) return;
    int node = nb16 + q;
    int nodec = node < n ? node : n - 1;
    float f0 = fc[nodec], f1 = fc[n + nodec], f2 = fc[2 * n + nodec], f3 = fc[3 * n + nodec];

    f32x4 ac[4], ag[4];
#pragma unroll
    for (int tc = 0; tc < 4; ++tc) { ac[tc] = (f32x4){0,0,0,0}; ag[tc] = (f32x4){0,0,0,0}; }

#pragma unroll
    for (int kk = 0; kk < 2; ++kk) {
        int off = kk * 32 + g * 8;
        bf16x8 a0r = *(const bf16x8*)(hpb + (size_t)nodec * 128 + off);   // Tx0 = h
        bf16x8 a1r = *(const bf16x8*)(Tx1b + (size_t)nodec * 64 + off);
        bf16x8 a2r = *(const bf16x8*)(Tx2b + (size_t)nodec * 64 + off);
        bf16x8 a3r = *(const bf16x8*)(Tx3b + (size_t)nodec * 64 + off);
        bf16x8 aA  = *(const bf16x8*)(aggb + (size_t)nodec * 64 + off);
        bf16x8 a0, a1, a2, a3;
#pragma unroll
        for (int j = 0; j < 8; ++j) {
            a0[j] = f2bf(f0 * bf2f((unsigned short)a0r[j]));
            a1[j] = f2bf(f1 * bf2f((unsigned short)a1r[j]));
            a2[j] = f2bf(f2 * bf2f((unsigned short)a2r[j]));
            a3[j] = f2bf(f3 * bf2f((unsigned short)a3r[j]));
        }
#pragma unroll
        for (int tc = 0; tc < 4; ++tc) {
            bf16x8 b0 = *(const bf16x8*)(WcT + 0 * 4096 + (tc * 16 + q) * 64 + off);
            bf16x8 b1 = *(const bf16x8*)(WcT + 1 * 4096 + (tc * 16 + q) * 64 + off);
            bf16x8 b2 = *(const bf16x8*)(WcT + 2 * 4096 + (tc * 16 + q) * 64 + off);
            bf16x8 b3 = *(const bf16x8*)(WcT + 3 * 4096 + (tc * 16 + q) * 64 + off);
            bf16x8 bgw = *(const bf16x8*)(WgT + (tc * 16 + q) * 64 + off);
            ac[tc] = __builtin_amdgcn_mfma_f32_16x16x32_bf16(a0, b0, ac[tc], 0, 0, 0);
            ac[tc] = __builtin_amdgcn_mfma_f32_16x16x32_bf16(a1, b1, ac[tc], 0, 0, 0);
            ac[tc] = __builtin_amdgcn_mfma_f32_16x16x32_bf16(a2, b2, ac[tc], 0, 0, 0);
            ac[tc] = __builtin_amdgcn_mfma_f32_16x16x32_bf16(a3, b3, ac[tc], 0, 0, 0);
            ag[tc] = __builtin_amdgcn_mfma_f32_16x16x32_bf16(aA, bgw, ag[tc], 0, 0, 0);
        }
    }
#pragma unroll
    for (int tc = 0; tc < 4; ++tc) {
        float bcv = bc[tc * 16 + q], bgv = bg[tc * 16 + q];
#pragma unroll
        for (int r = 0; r < 4; ++r) {
            int nd = nb16 + g * 4 + r;
            if (nd < n) {
                out[(size_t)nd * 192 + tc * 16 + q] = ac[tc][r] + bcv;
                out[(size_t)nd * 192 + 64 + tc * 16 + q] = ag[tc][r] + bgv;
            }
        }
    }
}

extern "C" void kernel_launch(void* const* d_in, const int* in_sizes, int n_in,
                              void* d_out, int out_size, void* d_ws, size_t ws_size,
                              hipStream_t stream) {
    const float* h  = (const float*)d_in[0];
    const float* p  = (const float*)d_in[1];
    const float* ef = (const float*)d_in[2];
    const float* ew = (const float*)d_in[3];
    const float* fc = (const float*)d_in[4];
    const int* esrc = (const int*)d_in[5];
    const int* edst = (const int*)d_in[6];
    const float* Wc = (const float*)d_in[7];
    const float* bc = (const float*)d_in[8];
    const float* Wg = (const float*)d_in[9];
    const float* bg = (const float*)d_in[10];
    const float* WQ = (const float*)d_in[11];
    const float* WK = (const float*)d_in[12];
    const float* WV = (const float*)d_in[13];
    const float* WE = (const float*)d_in[14];

    const int n = in_sizes[0] / DD;   // 50000
    const int E = in_sizes[5];        // 800000
    float* out = (float*)d_out;

    char* wsp = (char*)d_ws;
    size_t o = 0;
    auto alloc = [&](size_t bytes) -> void* {
        void* r = (void*)(wsp + o);
        o = (o + bytes + 255) & ~(size_t)255;
        return r;
    };
    int* deg     = (int*)alloc((size_t)n * 4);
    int* offsets = (int*)alloc((size_t)(n + 1) * 4);
    int* cursor  = (int*)alloc((size_t)n * 4);
    int4* payload = (int4*)alloc((size_t)E * 16);
    int* spos    = (int*)alloc((size_t)E * 4);
    int* dsts    = (int*)alloc((size_t)E * 4);
    int* bsum    = (int*)alloc(1024 * 4);
    float* dinv  = (float*)alloc((size_t)n * 4);
    short* WETb  = (short*)alloc(4096 * 2);
    unsigned short* WQTp = (unsigned short*)alloc(8192 * 2);
    unsigned short* WKTp = (unsigned short*)alloc(8192 * 2);
    unsigned short* WVT  = (unsigned short*)alloc(8192 * 2);
    unsigned short* WcT  = (unsigned short*)alloc(16384 * 2);
    unsigned short* WgT  = (unsigned short*)alloc(4096 * 2);
    unsigned short* hpb  = (unsigned short*)alloc((size_t)n * 128 * 2);
    unsigned short* Tx1b = (unsigned short*)alloc((size_t)n * DD * 2);
    unsigned short* Tx2b = (unsigned short*)alloc((size_t)n * DD * 2);
    unsigned short* Tx3b = (unsigned short*)alloc((size_t)n * DD * 2);
    unsigned short* aggb = (unsigned short*)alloc((size_t)n * DD * 2);
    unsigned short* Vhb  = (unsigned short*)alloc((size_t)n * DD * 2);
    unsigned short* Qhb  = (unsigned short*)alloc((size_t)n * DD * 2);
    unsigned short* Khb  = (unsigned short*)alloc((size_t)n * DD * 2);
    unsigned short* ssb  = (unsigned short*)alloc((size_t)E * HH * 2);
    (void)ws_size; (void)n_in; (void)out_size;

    hipMemsetAsync(deg, 0, (size_t)n * 4, stream);

    int nb = (n + 255) / 256;
    int CB = (E + 255) / 256;                 // count blocks
    int PRB = 128;                            // prep blocks (32768/256)
    int HB = (n * 64 + 255) / 256;            // hpb blocks
    fused_init<<<CB + PRB + HB, 256, 0, stream>>>(edst, E, deg, WQ, WK, WV, Wc, Wg, WE,
                                                  WQTp, WKTp, WVT, WcT, WgT, WETb,
                                                  h, p, n, hpb, CB, PRB);
    k_blocksum<<<nb, 256, 0, stream>>>(deg, n, bsum);
    k_scan_bsum<<<1, 256, 0, stream>>>(bsum, nb);
    k_scan_final<<<nb, 256, 0, stream>>>(deg, bsum, n, E, offsets, cursor, dinv);

    int SCB = (E + 255) / 256;
    fused_scatter<<<SCB + nb, 256, 0, stream>>>(edst, esrc, ew, dinv, E, cursor, payload,
                                                spos, offsets, n, dsts, SCB);

    int qkv_waves = (n + 15) / 16;
    int QB = (qkv_waves + 3) / 4;
    int PB = (n + 3) / 4;
    fused_qp<<<QB + PB, 256, 0, stream>>>(hpb, WQTp, WKTp, WVT, n, Qhb, Khb, Vhb,
                                          offsets, payload, dinv, Tx1b, aggb, QB);

    int SB = 1024;   // score blocks co-resident with lap blocks
    int LB = (n + 3) / 4;
    fused_sl<<<SB + LB, 256, 0, stream>>>(ef, WETb, esrc, edst, spos, payload, Qhb, Khb,
                                          E, ssb, offsets, dinv, Tx1b, hpb, n, Tx2b,
                                          SB, SB * 4);

    k_lap3_attn<<<(n + 3) / 4, 256, 0, stream>>>(offsets, payload, dinv, Tx2b, Tx1b, Vhb,
                                                 ssb, n, Tx3b, out);

    int out_waves = (n + 15) / 16;
    k_out<<<(out_waves + 3) / 4, 256, 0, stream>>>(hpb, Tx1b, Tx2b, Tx3b, aggb, fc,
                                                   WcT, WgT, bc, bg, n, out);
}